// Round 1
// baseline (1020.959 us; speedup 1.0000x reference)
//
#include <hip/hip_runtime.h>

#define EDGE_DIM 64
#define UPD 256

// ---------------------------------------------------------------------------
// Kernel 0: detect whether idx_i arrived as int64 or int32.
// If interpreted as int64 every value must be in [0, num_nodes); an int32
// buffer read as int64 packs two indices per word -> huge values -> detected.
// flag = 1 -> int64, flag = 0 -> int32.
// ---------------------------------------------------------------------------
__global__ void detect_idx_kernel(const void* __restrict__ idx, int n_edge,
                                  int num_nodes, int* __restrict__ flag) {
    if (threadIdx.x == 0) *flag = 1;
    __syncthreads();
    const long long* p = (const long long*)idx;
    int nchk = n_edge < 1024 ? n_edge : 1024;
    for (int i = threadIdx.x; i < nchk; i += blockDim.x) {
        long long v = p[i];
        if (v < 0 || v >= (long long)num_nodes) atomicExch(flag, 0);
    }
}

// ---------------------------------------------------------------------------
// Kernel 1: e = (rbf @ W_rbf) * x ; atomic scatter-add into h[idx_i].
// One wave per edge: lane = feature dim d (0..63).
// ---------------------------------------------------------------------------
__global__ __launch_bounds__(256) void edge_scatter_kernel(
    const float* __restrict__ x, const float* __restrict__ rbf,
    const void* __restrict__ idx_v, const float* __restrict__ Wrbf,
    float* __restrict__ h, const int* __restrict__ flag, int n_edge) {
    __shared__ float w[16 * EDGE_DIM];
    for (int i = threadIdx.x; i < 16 * EDGE_DIM; i += blockDim.x)
        w[i] = Wrbf[i];
    __syncthreads();

    const int use64 = *flag;
    const long long* idx64 = (const long long*)idx_v;
    const int* idx32 = (const int*)idx_v;

    const int lane = threadIdx.x & 63;
    const int wid = threadIdx.x >> 6;
    const int wpb = blockDim.x >> 6;
    const long long stride = (long long)gridDim.x * wpb;

    for (long long e = (long long)blockIdx.x * wpb + wid; e < n_edge; e += stride) {
        float r = rbf[e * 16 + (lane & 15)];
        float s = 0.f;
#pragma unroll
        for (int q = 0; q < 16; ++q)
            s = fmaf(__shfl(r, q), w[q * EDGE_DIM + lane], s);
        float xv = x[e * EDGE_DIM + lane];
        long long node = use64 ? idx64[e] : (long long)idx32[e];
        atomicAdd(&h[node * EDGE_DIM + lane], s * xv);
    }
}

// ---------------------------------------------------------------------------
// Kernel 2: fused node MLP.
// Per block: 64 nodes. LDS ping-pong activation buffers (64x256 f32 each)
// plus a 16x256 streamed weight tile. 512 threads; each thread owns a
// 4-node x 8-dim register tile (32 accumulators).
// ---------------------------------------------------------------------------
__global__ __launch_bounds__(512) void node_mlp_kernel(
    const float* __restrict__ h_in,  // [nn, 64]
    const float* __restrict__ W_up,  // [64, 256]
    const float* __restrict__ W1, const float* __restrict__ b1,
    const float* __restrict__ W2, const float* __restrict__ b2,
    const float* __restrict__ W3, const float* __restrict__ b3,
    const float* __restrict__ W_out,  // [256]
    float* __restrict__ out, int nn) {
    __shared__ float Ba[64 * UPD];
    __shared__ float Bb[64 * UPD];
    __shared__ float Wt[16 * UPD];

    const int tid = threadIdx.x;
    const int node0 = blockIdx.x * 64;
    const int ty = tid >> 5, tx = tid & 31;
    const int n0 = ty * 4, d0 = tx * 8;

    // Load h tile (64 x 64) into Ba rows (stride UPD), zero-pad tail nodes.
    for (int F = tid; F < 64 * EDGE_DIM / 4; F += 512) {
        int n = F >> 4;
        int c = (F & 15) << 2;
        float4 v = {0.f, 0.f, 0.f, 0.f};
        if (node0 + n < nn)
            v = *(const float4*)&h_in[(long long)(node0 + n) * EDGE_DIM + c];
        *(float4*)&Ba[n * UPD + c] = v;
    }

    auto layer = [&](const float* Bin, float* Bout, const float* Wg,
                     const float* bg, int K, bool act) {
        float acc[4][8];
#pragma unroll
        for (int i = 0; i < 4; ++i)
#pragma unroll
            for (int j = 0; j < 8; ++j) acc[i][j] = 0.f;

        for (int kt = 0; kt < K; kt += 16) {
            __syncthreads();  // protect Wt reuse + Bin handoff
            // Stage 16x256 weight tile: 1024 float4 / 512 threads = 2 each.
#pragma unroll
            for (int it = 0; it < 2; ++it) {
                int F = tid + it * 512;
                int r = F >> 6, c = (F & 63) << 2;
                *(float4*)&Wt[r * UPD + c] =
                    *(const float4*)&Wg[(long long)(kt + r) * UPD + c];
            }
            __syncthreads();
#pragma unroll
            for (int kk = 0; kk < 16; kk += 4) {
                float4 a[4];
#pragma unroll
                for (int i = 0; i < 4; ++i)
                    a[i] = *(const float4*)&Bin[(n0 + i) * UPD + kt + kk];
#pragma unroll
                for (int q = 0; q < 4; ++q) {
                    float4 w0 = *(const float4*)&Wt[(kk + q) * UPD + d0];
                    float4 w1 = *(const float4*)&Wt[(kk + q) * UPD + d0 + 4];
                    float wv[8] = {w0.x, w0.y, w0.z, w0.w,
                                   w1.x, w1.y, w1.z, w1.w};
#pragma unroll
                    for (int i = 0; i < 4; ++i) {
                        float av = ((const float*)&a[i])[q];
#pragma unroll
                        for (int j = 0; j < 8; ++j)
                            acc[i][j] = fmaf(av, wv[j], acc[i][j]);
                    }
                }
            }
        }

        float bv[8] = {0, 0, 0, 0, 0, 0, 0, 0};
        if (bg) {
            float4 c0 = *(const float4*)&bg[d0];
            float4 c1 = *(const float4*)&bg[d0 + 4];
            bv[0] = c0.x; bv[1] = c0.y; bv[2] = c0.z; bv[3] = c0.w;
            bv[4] = c1.x; bv[5] = c1.y; bv[6] = c1.z; bv[7] = c1.w;
        }
#pragma unroll
        for (int i = 0; i < 4; ++i) {
            float o[8];
#pragma unroll
            for (int j = 0; j < 8; ++j) {
                float v = acc[i][j] + bv[j];
                if (act) v = v / (1.f + __expf(-v));  // silu
                o[j] = v;
            }
            *(float4*)&Bout[(n0 + i) * UPD + d0] =
                make_float4(o[0], o[1], o[2], o[3]);
            *(float4*)&Bout[(n0 + i) * UPD + d0 + 4] =
                make_float4(o[4], o[5], o[6], o[7]);
        }
    };

    layer(Ba, Bb, W_up, nullptr, EDGE_DIM, false);
    layer(Bb, Ba, W1, b1, UPD, true);
    layer(Ba, Bb, W2, b2, UPD, true);
    layer(Bb, Ba, W3, b3, UPD, true);

    __syncthreads();
    // Output head: 8 threads per node, each sums 32 of 256.
    int n = tid >> 3, p = tid & 7;
    float s = 0.f;
    for (int k = p * 32; k < p * 32 + 32; k += 4) {
        float4 v = *(const float4*)&Ba[n * UPD + k];
        float4 wv = *(const float4*)&W_out[k];
        s = fmaf(v.x, wv.x, s);
        s = fmaf(v.y, wv.y, s);
        s = fmaf(v.z, wv.z, s);
        s = fmaf(v.w, wv.w, s);
    }
    s += __shfl_xor(s, 1);
    s += __shfl_xor(s, 2);
    s += __shfl_xor(s, 4);
    if (p == 0 && node0 + n < nn) out[node0 + n] = s;
}

// ---------------------------------------------------------------------------
extern "C" void kernel_launch(void* const* d_in, const int* in_sizes, int n_in,
                              void* d_out, int out_size, void* d_ws, size_t ws_size,
                              hipStream_t stream) {
    const float* x     = (const float*)d_in[0];
    const float* rbf   = (const float*)d_in[1];
    const void*  idx   = d_in[2];
    // d_in[3] = num_nodes scalar (dtype ambiguous) -> use out_size instead.
    const float* W_rbf = (const float*)d_in[4];
    const float* W_up  = (const float*)d_in[5];
    const float* W1    = (const float*)d_in[6];
    const float* b1    = (const float*)d_in[7];
    const float* W2    = (const float*)d_in[8];
    const float* b2    = (const float*)d_in[9];
    const float* W3    = (const float*)d_in[10];
    const float* b3    = (const float*)d_in[11];
    const float* W_out = (const float*)d_in[12];
    float* out = (float*)d_out;

    const int n_edge = in_sizes[0] / EDGE_DIM;
    const int nn = out_size;  // out_dim == 1

    float* h = (float*)d_ws;
    size_t h_bytes = (size_t)nn * EDGE_DIM * sizeof(float);
    int* flag = (int*)((char*)d_ws + h_bytes);

    hipMemsetAsync(d_ws, 0, h_bytes, stream);
    detect_idx_kernel<<<1, 256, 0, stream>>>(idx, n_edge, nn, flag);
    edge_scatter_kernel<<<2048, 256, 0, stream>>>(x, rbf, idx, W_rbf, h, flag,
                                                  n_edge);
    const int nb = (nn + 63) / 64;
    node_mlp_kernel<<<nb, 512, 0, stream>>>(h, W_up, W1, b1, W2, b2, W3, b3,
                                            W_out, out, nn);
}

// Round 2
// 411.971 us; speedup vs baseline: 2.4782x; 2.4782x over previous
//
#include <hip/hip_runtime.h>
#include <hip/hip_bf16.h>

#define EDGE_DIM 64
#define UPD 256

typedef __attribute__((ext_vector_type(8))) short bf16x8;
typedef __attribute__((ext_vector_type(4))) float f32x4;

__device__ __forceinline__ short f2bf(float v) {
    __hip_bfloat16 b = __float2bfloat16(v);
    return *(short*)&b;
}
__device__ __forceinline__ float bf2f(short s) {
    __hip_bfloat16 b = *(__hip_bfloat16*)&s;
    return __bfloat162float(b);
}

// ---------------------------------------------------------------------------
// Kernel 0: detect int64 vs int32 idx (flag=1 -> int64).
// ---------------------------------------------------------------------------
__global__ void detect_idx_kernel(const void* __restrict__ idx, int n_edge,
                                  int num_nodes, int* __restrict__ flag) {
    if (threadIdx.x == 0) *flag = 1;
    __syncthreads();
    const long long* p = (const long long*)idx;
    int nchk = n_edge < 1024 ? n_edge : 1024;
    for (int i = threadIdx.x; i < nchk; i += blockDim.x) {
        long long v = p[i];
        if (v < 0 || v >= (long long)num_nodes) atomicExch(flag, 0);
    }
}

// ---------------------------------------------------------------------------
// Kernel 1: pack weight matrix W [K][256] f32 into MFMA-fragment order,
// split into bf16 hi/lo. Fragment (kt,nt): lane l elem j holds
// W[kt*32 + 8*(l>>4) + j][nt*16 + (l&15)]. Storage: frag f = kt*16+nt,
// hi at shorts [f*1024 + l*8 + j], lo at [f*1024 + 512 + l*8 + j].
// ---------------------------------------------------------------------------
__global__ void pack_w_kernel(const float* __restrict__ W,
                              short* __restrict__ out, int K) {
    int t = blockIdx.x * blockDim.x + threadIdx.x;
    int nfrag = (K / 32) * 16;
    if (t >= nfrag * 64) return;
    int l = t & 63, f = t >> 6;
    int kt = f >> 4, nt = f & 15;
    int kbase = kt * 32 + (l >> 4) * 8;
    int col = nt * 16 + (l & 15);
#pragma unroll
    for (int j = 0; j < 8; ++j) {
        float v = W[(kbase + j) * UPD + col];
        short hb = f2bf(v);
        short lb = f2bf(v - bf2f(hb));
        out[f * 1024 + l * 8 + j] = hb;
        out[f * 1024 + 512 + l * 8 + j] = lb;
    }
}

// ---------------------------------------------------------------------------
// Kernel 2: edge gate + scatter-add (unchanged).
// ---------------------------------------------------------------------------
__global__ __launch_bounds__(256) void edge_scatter_kernel(
    const float* __restrict__ x, const float* __restrict__ rbf,
    const void* __restrict__ idx_v, const float* __restrict__ Wrbf,
    float* __restrict__ h, const int* __restrict__ flag, int n_edge) {
    __shared__ float w[16 * EDGE_DIM];
    for (int i = threadIdx.x; i < 16 * EDGE_DIM; i += blockDim.x)
        w[i] = Wrbf[i];
    __syncthreads();

    const int use64 = *flag;
    const long long* idx64 = (const long long*)idx_v;
    const int* idx32 = (const int*)idx_v;

    const int lane = threadIdx.x & 63;
    const int wid = threadIdx.x >> 6;
    const int wpb = blockDim.x >> 6;
    const long long stride = (long long)gridDim.x * wpb;

    for (long long e = (long long)blockIdx.x * wpb + wid; e < n_edge; e += stride) {
        float r = rbf[e * 16 + (lane & 15)];
        float s = 0.f;
#pragma unroll
        for (int q = 0; q < 16; ++q)
            s = fmaf(__shfl(r, q), w[q * EDGE_DIM + lane], s);
        float xv = x[e * EDGE_DIM + lane];
        long long node = use64 ? idx64[e] : (long long)idx32[e];
        atomicAdd(&h[node * EDGE_DIM + lane], s * xv);
    }
}

// ---------------------------------------------------------------------------
// MFMA node MLP. Block = 64 nodes, 256 threads = 4 waves; wave wq owns output
// cols [wq*64, wq*64+64). Activations in LDS as separate hi/lo bf16 arrays
// [64][256], XOR-swizzled 16B chunks (chunk ^= row&7). In-place across layers.
// ---------------------------------------------------------------------------
template <int NK>
__device__ __forceinline__ void mm_layer(const short* AH, const short* AL,
                                         const short* __restrict__ Wpk,
                                         int lr, int lh, int lane, int wq,
                                         f32x4 acc[4][4]) {
#pragma unroll
    for (int kt = 0; kt < NK; ++kt) {
        bf16x8 a[4][2];
#pragma unroll
        for (int m = 0; m < 4; ++m) {
            int r = m * 16 + lr;
            int ch = (kt * 4 + lh) ^ (r & 7);
            int off = r * 256 + ch * 8;  // shorts
            a[m][0] = *(const bf16x8*)(AH + off);
            a[m][1] = *(const bf16x8*)(AL + off);
        }
        bf16x8 b[4][2];
#pragma unroll
        for (int nf = 0; nf < 4; ++nf) {
            int f = kt * 16 + wq * 4 + nf;
            const short* p = Wpk + f * 1024 + lane * 8;
            b[nf][0] = *(const bf16x8*)(p);
            b[nf][1] = *(const bf16x8*)(p + 512);
        }
#pragma unroll
        for (int m = 0; m < 4; ++m)
#pragma unroll
            for (int nf = 0; nf < 4; ++nf) {
                acc[m][nf] = __builtin_amdgcn_mfma_f32_16x16x32_bf16(
                    a[m][0], b[nf][0], acc[m][nf], 0, 0, 0);
                acc[m][nf] = __builtin_amdgcn_mfma_f32_16x16x32_bf16(
                    a[m][0], b[nf][1], acc[m][nf], 0, 0, 0);
                acc[m][nf] = __builtin_amdgcn_mfma_f32_16x16x32_bf16(
                    a[m][1], b[nf][0], acc[m][nf], 0, 0, 0);
            }
    }
}

template <bool ACT>
__device__ __forceinline__ void epilogue_store(f32x4 acc[4][4], short* AH,
                                               short* AL,
                                               const float* __restrict__ bias,
                                               int lr, int lh, int wq) {
    float bv[4] = {0.f, 0.f, 0.f, 0.f};
    if (bias) {
#pragma unroll
        for (int nf = 0; nf < 4; ++nf) bv[nf] = bias[wq * 64 + nf * 16 + lr];
    }
#pragma unroll
    for (int m = 0; m < 4; ++m)
#pragma unroll
        for (int nf = 0; nf < 4; ++nf) {
            int c = wq * 64 + nf * 16 + lr;
#pragma unroll
            for (int reg = 0; reg < 4; ++reg) {
                float v = acc[m][nf][reg] + bv[nf];
                if (ACT) v = v / (1.f + __expf(-v));
                int r = m * 16 + lh * 4 + reg;
                short hb = f2bf(v);
                short lb = f2bf(v - bf2f(hb));
                int off = r * 256 + (((c >> 3) ^ (r & 7)) * 8) + (c & 7);
                AH[off] = hb;
                AL[off] = lb;
            }
        }
}

__global__ __launch_bounds__(256, 2) void node_mlp_mfma(
    const float* __restrict__ h,
    const short* __restrict__ Wup_pk, const short* __restrict__ W1_pk,
    const short* __restrict__ W2_pk, const short* __restrict__ W3_pk,
    const float* __restrict__ b1, const float* __restrict__ b2,
    const float* __restrict__ b3, const float* __restrict__ W_out,
    float* __restrict__ out, int nn) {
    __shared__ short AH[64 * 256];
    __shared__ short AL[64 * 256];
    __shared__ float Bpart[64 * 4];

    const int tid = threadIdx.x;
    const int lane = tid & 63, wq = tid >> 6;
    const int lr = lane & 15, lh = lane >> 4;
    const int node0 = blockIdx.x * 64;

    // Stage h tile (64 x 64 f32) -> hi/lo bf16, swizzled, cols 0..63.
#pragma unroll
    for (int i = 0; i < 4; ++i) {
        int idx4 = tid + i * 256;  // 0..1023 float4s
        int r = idx4 >> 4, c4 = idx4 & 15;
        float4 v = {0.f, 0.f, 0.f, 0.f};
        if (node0 + r < nn)
            v = *(const float4*)(h + (long long)(node0 + r) * EDGE_DIM + c4 * 4);
        short h0 = f2bf(v.x), h1 = f2bf(v.y), h2 = f2bf(v.z), h3 = f2bf(v.w);
        short l0 = f2bf(v.x - bf2f(h0)), l1 = f2bf(v.y - bf2f(h1));
        short l2 = f2bf(v.z - bf2f(h2)), l3 = f2bf(v.w - bf2f(h3));
        int off = r * 256 + (((c4 >> 1) ^ (r & 7)) * 8) + (c4 & 1) * 4;
        uint2 hw, lw;
        hw.x = (unsigned short)h0 | ((unsigned)(unsigned short)h1 << 16);
        hw.y = (unsigned short)h2 | ((unsigned)(unsigned short)h3 << 16);
        lw.x = (unsigned short)l0 | ((unsigned)(unsigned short)l1 << 16);
        lw.y = (unsigned short)l2 | ((unsigned)(unsigned short)l3 << 16);
        *(uint2*)(AH + off) = hw;
        *(uint2*)(AL + off) = lw;
    }
    __syncthreads();

    f32x4 acc[4][4];

    // Layer up: K=64, no bias, no act.
#pragma unroll
    for (int m = 0; m < 4; ++m)
#pragma unroll
        for (int n = 0; n < 4; ++n) acc[m][n] = (f32x4){0.f, 0.f, 0.f, 0.f};
    mm_layer<2>(AH, AL, Wup_pk, lr, lh, lane, wq, acc);
    __syncthreads();
    epilogue_store<false>(acc, AH, AL, nullptr, lr, lh, wq);
    __syncthreads();

    // Layer 1
#pragma unroll
    for (int m = 0; m < 4; ++m)
#pragma unroll
        for (int n = 0; n < 4; ++n) acc[m][n] = (f32x4){0.f, 0.f, 0.f, 0.f};
    mm_layer<8>(AH, AL, W1_pk, lr, lh, lane, wq, acc);
    __syncthreads();
    epilogue_store<true>(acc, AH, AL, b1, lr, lh, wq);
    __syncthreads();

    // Layer 2
#pragma unroll
    for (int m = 0; m < 4; ++m)
#pragma unroll
        for (int n = 0; n < 4; ++n) acc[m][n] = (f32x4){0.f, 0.f, 0.f, 0.f};
    mm_layer<8>(AH, AL, W2_pk, lr, lh, lane, wq, acc);
    __syncthreads();
    epilogue_store<true>(acc, AH, AL, b2, lr, lh, wq);
    __syncthreads();

    // Layer 3 + fused head: out = silu(acc + b3) . W_out
#pragma unroll
    for (int m = 0; m < 4; ++m)
#pragma unroll
        for (int n = 0; n < 4; ++n) acc[m][n] = (f32x4){0.f, 0.f, 0.f, 0.f};
    mm_layer<8>(AH, AL, W3_pk, lr, lh, lane, wq, acc);

    float b3v[4], wo[4];
#pragma unroll
    for (int nf = 0; nf < 4; ++nf) {
        int c = wq * 64 + nf * 16 + lr;
        b3v[nf] = b3[c];
        wo[nf] = W_out[c];
    }
#pragma unroll
    for (int m = 0; m < 4; ++m) {
#pragma unroll
        for (int reg = 0; reg < 4; ++reg) {
            float s = 0.f;
#pragma unroll
            for (int nf = 0; nf < 4; ++nf) {
                float v = acc[m][nf][reg] + b3v[nf];
                v = v / (1.f + __expf(-v));
                s = fmaf(v, wo[nf], s);
            }
            s += __shfl_xor(s, 1);
            s += __shfl_xor(s, 2);
            s += __shfl_xor(s, 4);
            s += __shfl_xor(s, 8);
            if (lr == 0) Bpart[(m * 16 + lh * 4 + reg) * 4 + wq] = s;
        }
    }
    __syncthreads();
    if (tid < 64) {
        float s = Bpart[tid * 4] + Bpart[tid * 4 + 1] + Bpart[tid * 4 + 2] +
                  Bpart[tid * 4 + 3];
        if (node0 + tid < nn) out[node0 + tid] = s;
    }
}

// ---------------------------------------------------------------------------
extern "C" void kernel_launch(void* const* d_in, const int* in_sizes, int n_in,
                              void* d_out, int out_size, void* d_ws, size_t ws_size,
                              hipStream_t stream) {
    const float* x     = (const float*)d_in[0];
    const float* rbf   = (const float*)d_in[1];
    const void*  idx   = d_in[2];
    const float* W_rbf = (const float*)d_in[4];
    const float* W_up  = (const float*)d_in[5];
    const float* W1    = (const float*)d_in[6];
    const float* b1    = (const float*)d_in[7];
    const float* W2    = (const float*)d_in[8];
    const float* b2    = (const float*)d_in[9];
    const float* W3    = (const float*)d_in[10];
    const float* b3    = (const float*)d_in[11];
    const float* W_out = (const float*)d_in[12];
    float* out = (float*)d_out;

    const int n_edge = in_sizes[0] / EDGE_DIM;
    const int nn = out_size;

    float* h = (float*)d_ws;
    size_t h_bytes = (size_t)nn * EDGE_DIM * sizeof(float);
    short* wup_pk = (short*)((char*)d_ws + h_bytes);      // 32 frags * 1024
    short* w1_pk = wup_pk + 32 * 1024;                    // 128 frags * 1024
    short* w2_pk = w1_pk + 128 * 1024;
    short* w3_pk = w2_pk + 128 * 1024;
    int* flag = (int*)(w3_pk + 128 * 1024);

    hipMemsetAsync(h, 0, h_bytes, stream);
    detect_idx_kernel<<<1, 256, 0, stream>>>(idx, n_edge, nn, flag);
    pack_w_kernel<<<8, 256, 0, stream>>>(W_up, wup_pk, 64);
    pack_w_kernel<<<32, 256, 0, stream>>>(W1, w1_pk, 256);
    pack_w_kernel<<<32, 256, 0, stream>>>(W2, w2_pk, 256);
    pack_w_kernel<<<32, 256, 0, stream>>>(W3, w3_pk, 256);
    edge_scatter_kernel<<<2048, 256, 0, stream>>>(x, rbf, idx, W_rbf, h, flag,
                                                  n_edge);
    const int nb = (nn + 63) / 64;
    node_mlp_mfma<<<nb, 256, 0, stream>>>(h, wup_pk, w1_pk, w2_pk, w3_pk,
                                          b1, b2, b3, W_out, out, nn);
}